// Round 11
// baseline (63.007 us; speedup 1.0000x reference)
//
#include <hip/hip_runtime.h>
#include <hip/hip_bf16.h>
#include <utility>

#define LOG2E 1.4426950408889634f

#if __has_builtin(__builtin_amdgcn_exp2f)
#define EXP2F(x) __builtin_amdgcn_exp2f(x)
#else
#define EXP2F(x) exp2f(x)
#endif

#if __has_builtin(__builtin_amdgcn_rsqf)
#define RSQ(x) __builtin_amdgcn_rsqf(x)
#else
#define RSQ(x) (1.0f / sqrtf(x))
#endif

// readlane: lane may be a literal OR a runtime-uniform (SGPR) value.
#define RDLANE(x, l) __int_as_float(__builtin_amdgcn_readlane(__float_as_int(x), (l)))

// ---------------------------------------------------------------------------
// Kernel 1 (byte-identical to R9): rolled-outer / padded-unrolled-inner
// Cholesky, one wave. R9 evidence: dropped out of rocprof top-5 (was 117us
// profiled in R8) -- code-size/icache theory confirmed.
// ---------------------------------------------------------------------------
typedef float f16v __attribute__((ext_vector_type(16)));
struct Rows { f16v v0, v1, v2, v3; };

template<int J> __device__ __forceinline__ float getR(const Rows& r) {
    if constexpr (J < 16)      return r.v0[J];
    else if constexpr (J < 32) return r.v1[J - 16];
    else if constexpr (J < 48) return r.v2[J - 32];
    else                       return r.v3[J - 48];
}
template<int J> __device__ __forceinline__ void setR(Rows& r, float x) {
    if constexpr (J < 16)      r.v0[J] = x;
    else if constexpr (J < 32) r.v1[J - 16] = x;
    else if constexpr (J < 48) r.v2[J - 32] = x;
    else                       r.v3[J - 48] = x;
}

template<int LO, int W>
__device__ __forceinline__ float selR(const Rows& r, int k) {
    if constexpr (W == 1) {
        return getR<LO>(r);
    } else {
        float lo = selR<LO, W / 2>(r, k);
        float hi = selR<LO + W / 2, W / 2>(r, k);
        return (k & (W / 2)) ? hi : lo;   // uniform cond -> cndmask, CSE'd
    }
}

template<int J>
__device__ __forceinline__ void upd1(Rows& r, float lk) {
    float ljk = RDLANE(lk, J);                 // literal source lane
    setR<J>(r, fmaf(-lk, ljk, getR<J>(r)));
}
template<int LO, int... Js>
__device__ __forceinline__ void upd_seq(Rows& r, float lk,
                                        std::integer_sequence<int, Js...>) {
    (upd1<LO + Js>(r, lk), ...);
}

template<int... Js>
__device__ __forceinline__ void load_row(Rows& r, const float* Lrow,
                                         std::integer_sequence<int, Js...>) {
    (setR<Js>(r, Lrow[Js]), ...);
}

template<int KLO, int KHI, int ULO>
__device__ __forceinline__ void chol_phase(Rows& r, float* Lsh, int lane) {
#pragma clang loop unroll(disable)
    for (int k = KLO; k < KHI; ++k) {
        float rk  = selR<ULO, 64 - ULO>(r, k); // A[l][k] (valid l >= k)
        float dk  = RDLANE(rk, k);             // A[k][k], uniform
        float inv = RSQ(dk);                   // 1/L[k][k]
        float lk  = rk * inv;                  // L[l][k]
        float st  = (lane == k) ? inv : lk;    // diag slot stores reciprocal
        Lsh[lane * 65 + k] = st;               // sink column k (conflict-free)
        upd_seq<ULO>(r, lk, std::make_integer_sequence<int, 64 - ULO>{});
    }
}

__global__ __launch_bounds__(64, 1)
void gp_precompute(const float* __restrict__ Z, const float* __restrict__ U,
                   const float* __restrict__ sf_p, const float* __restrict__ ell_p,
                   float* __restrict__ ws) {
    __shared__ float Lsh[64 * 65];
    const int lane = threadIdx.x;          // 64 threads = 1 wave
    const float sf  = sf_p[0];
    const float ell = ell_p[0];
    const float inv_ell = 1.0f / ell;
    const float sf2 = sf * sf;

    const float z0 = Z[lane * 3 + 0] * inv_ell;
    const float z1 = Z[lane * 3 + 1] * inv_ell;
    const float z2 = Z[lane * 3 + 2] * inv_ell;

#pragma clang loop unroll(disable)
    for (int j = 0; j < 64; ++j) {
        float dx = z0 - RDLANE(z0, j);
        float dy = z1 - RDLANE(z1, j);
        float dz = z2 - RDLANE(z2, j);
        float sq = dx * dx + dy * dy + dz * dz;
        Lsh[lane * 65 + j] = sf2 * EXP2F(-0.5f * LOG2E * sq);
    }
    __syncthreads();

    Rows r;
    load_row(r, &Lsh[lane * 65], std::make_integer_sequence<int, 64>{});

    chol_phase< 0, 32,  0>(r, Lsh, lane);
    chol_phase<32, 48, 32>(r, Lsh, lane);
    chol_phase<48, 64, 48>(r, Lsh, lane);
    __syncthreads();

    float s0 = U[lane * 2 + 0];
    float s1 = U[lane * 2 + 1];
    float w0v = 0.0f, w1v = 0.0f;
#pragma unroll 8
    for (int i = 63; i >= 0; --i) {
        float a   = Lsh[i * 65 + lane];    // L[i][lane]; lane i: 1/L[i][i]
        float rdi = RDLANE(a, i);          // 1/L[i][i]
        float w0  = RDLANE(s0, i) * rdi;   // W[i][0]
        float w1  = RDLANE(s1, i) * rdi;   // W[i][1]
        bool  me  = (lane == i);
        w0v = me ? w0 : w0v;
        w1v = me ? w1 : w1v;
        s0 = fmaf(-a, w0, s0);             // lanes >= i polluted after use
        s1 = fmaf(-a, w1, s1);
    }

    const float dm = -0.5f * LOG2E * (z0 * z0 + z1 * z1 + z2 * z2);
    float4* ws4 = (float4*)ws;
    ws4[lane * 2 + 0] = make_float4(z0, z1, z2, dm);
    ws4[lane * 2 + 1] = make_float4(sf2 * w0v, sf2 * w1v, 0.0f, 0.0f);
}

// ---------------------------------------------------------------------------
// Kernel 2, R10: per-m constants via SGPRs instead of LDS.
// All ws[8m+c] reads have wave-uniform addresses with compile-time m ->
// scalar loads (s_load_dwordx8 per m) through the constant cache. Each VALU
// op consumes its one allowed SGPR operand (v_fma v,s,v,v / v_add v,s,v /
// v_fma v,s,v for the accumulate). No LDS, no __syncthreads, pure VALU+trans
// issue in the m-loop.
// ---------------------------------------------------------------------------
__global__ __launch_bounds__(256) void gp_forward(const float* __restrict__ X,
                                                  const float* __restrict__ ws,
                                                  const float* __restrict__ ell_p,
                                                  float* __restrict__ out, int n) {
    const float inv_ell = 1.0f / ell_p[0];     // uniform -> s_load

    const int base = blockIdx.x * (256 * 4) + threadIdx.x;

    float xt0[4], xt1[4], xt2[4], c[4];
#pragma unroll
    for (int p = 0; p < 4; ++p) {
        int i = base + p * 256;
        int ii = (i < n) ? i : 0;            // clamp; result masked on store
        float xs0 = X[ii * 3 + 0] * inv_ell;
        float xs1 = X[ii * 3 + 1] * inv_ell;
        float xs2 = X[ii * 3 + 2] * inv_ell;
        c[p]  = -0.5f * LOG2E * (xs0 * xs0 + xs1 * xs1 + xs2 * xs2);
        xt0[p] = xs0 * LOG2E;
        xt1[p] = xs1 * LOG2E;
        xt2[p] = xs2 * LOG2E;
    }

    float acc0[4] = {0.f, 0.f, 0.f, 0.f};
    float acc1[4] = {0.f, 0.f, 0.f, 0.f};

#pragma unroll
    for (int m = 0; m < 64; ++m) {
        // Wave-uniform, compile-time offsets -> scalar loads (one dwordx8/m).
        const float z0 = ws[8 * m + 0];
        const float z1 = ws[8 * m + 1];
        const float z2 = ws[8 * m + 2];
        const float dm = ws[8 * m + 3];
        const float w0 = ws[8 * m + 4];
        const float w1 = ws[8 * m + 5];
#pragma unroll
        for (int p = 0; p < 4; ++p) {
            float arg = fmaf(xt0[p], z0,
                        fmaf(xt1[p], z1,
                        fmaf(xt2[p], z2, c[p] + dm)));
            float e = EXP2F(arg);
            acc0[p] = fmaf(e, w0, acc0[p]);
            acc1[p] = fmaf(e, w1, acc1[p]);
        }
    }

    float2* out2 = (float2*)out;
#pragma unroll
    for (int p = 0; p < 4; ++p) {
        int i = base + p * 256;
        if (i < n) out2[i] = make_float2(acc0[p], acc1[p]);
    }
}

extern "C" void kernel_launch(void* const* d_in, const int* in_sizes, int n_in,
                              void* d_out, int out_size, void* d_ws, size_t ws_size,
                              hipStream_t stream) {
    // setup_inputs order: t, X, Z, U, sf, ell
    const float* X    = (const float*)d_in[1];
    const float* Z    = (const float*)d_in[2];
    const float* U    = (const float*)d_in[3];
    const float* sf   = (const float*)d_in[4];
    const float* ell  = (const float*)d_in[5];
    float* out = (float*)d_out;
    float* ws  = (float*)d_ws;
    const int N = in_sizes[1] / 3;

    gp_precompute<<<1, 64, 0, stream>>>(Z, U, sf, ell, ws);

    const int PTS_PER_BLOCK = 256 * 4;
    const int blocks = (N + PTS_PER_BLOCK - 1) / PTS_PER_BLOCK;
    gp_forward<<<blocks, 256, 0, stream>>>(X, ws, ell, out, N);
}

// Round 12
// 58.217 us; speedup vs baseline: 1.0823x; 1.0823x over previous
//
#include <hip/hip_runtime.h>
#include <hip/hip_bf16.h>
#include <utility>

#define LOG2E 1.4426950408889634f

#if __has_builtin(__builtin_amdgcn_exp2f)
#define EXP2F(x) __builtin_amdgcn_exp2f(x)
#else
#define EXP2F(x) exp2f(x)
#endif

#if __has_builtin(__builtin_amdgcn_rsqf)
#define RSQ(x) __builtin_amdgcn_rsqf(x)
#else
#define RSQ(x) (1.0f / sqrtf(x))
#endif

// readlane: lane may be a literal OR a runtime-uniform (SGPR) value.
#define RDLANE(x, l) __int_as_float(__builtin_amdgcn_readlane(__float_as_int(x), (l)))

// ---------------------------------------------------------------------------
// Kernel 1 (byte-identical to R9): rolled-outer / padded-unrolled-inner
// Cholesky, one wave. R9 evidence: dropped out of rocprof top-5 (was 117us
// profiled in R8) -- code-size/icache theory confirmed.
// ---------------------------------------------------------------------------
typedef float f16v __attribute__((ext_vector_type(16)));
struct Rows { f16v v0, v1, v2, v3; };

template<int J> __device__ __forceinline__ float getR(const Rows& r) {
    if constexpr (J < 16)      return r.v0[J];
    else if constexpr (J < 32) return r.v1[J - 16];
    else if constexpr (J < 48) return r.v2[J - 32];
    else                       return r.v3[J - 48];
}
template<int J> __device__ __forceinline__ void setR(Rows& r, float x) {
    if constexpr (J < 16)      r.v0[J] = x;
    else if constexpr (J < 32) r.v1[J - 16] = x;
    else if constexpr (J < 48) r.v2[J - 32] = x;
    else                       r.v3[J - 48] = x;
}

template<int LO, int W>
__device__ __forceinline__ float selR(const Rows& r, int k) {
    if constexpr (W == 1) {
        return getR<LO>(r);
    } else {
        float lo = selR<LO, W / 2>(r, k);
        float hi = selR<LO + W / 2, W / 2>(r, k);
        return (k & (W / 2)) ? hi : lo;   // uniform cond -> cndmask, CSE'd
    }
}

template<int J>
__device__ __forceinline__ void upd1(Rows& r, float lk) {
    float ljk = RDLANE(lk, J);                 // literal source lane
    setR<J>(r, fmaf(-lk, ljk, getR<J>(r)));
}
template<int LO, int... Js>
__device__ __forceinline__ void upd_seq(Rows& r, float lk,
                                        std::integer_sequence<int, Js...>) {
    (upd1<LO + Js>(r, lk), ...);
}

template<int... Js>
__device__ __forceinline__ void load_row(Rows& r, const float* Lrow,
                                         std::integer_sequence<int, Js...>) {
    (setR<Js>(r, Lrow[Js]), ...);
}

template<int KLO, int KHI, int ULO>
__device__ __forceinline__ void chol_phase(Rows& r, float* Lsh, int lane) {
#pragma clang loop unroll(disable)
    for (int k = KLO; k < KHI; ++k) {
        float rk  = selR<ULO, 64 - ULO>(r, k); // A[l][k] (valid l >= k)
        float dk  = RDLANE(rk, k);             // A[k][k], uniform
        float inv = RSQ(dk);                   // 1/L[k][k]
        float lk  = rk * inv;                  // L[l][k]
        float st  = (lane == k) ? inv : lk;    // diag slot stores reciprocal
        Lsh[lane * 65 + k] = st;               // sink column k (conflict-free)
        upd_seq<ULO>(r, lk, std::make_integer_sequence<int, 64 - ULO>{});
    }
}

__global__ __launch_bounds__(64, 1)
void gp_precompute(const float* __restrict__ Z, const float* __restrict__ U,
                   const float* __restrict__ sf_p, const float* __restrict__ ell_p,
                   float* __restrict__ ws) {
    __shared__ float Lsh[64 * 65];
    const int lane = threadIdx.x;          // 64 threads = 1 wave
    const float sf  = sf_p[0];
    const float ell = ell_p[0];
    const float inv_ell = 1.0f / ell;
    const float sf2 = sf * sf;

    const float z0 = Z[lane * 3 + 0] * inv_ell;
    const float z1 = Z[lane * 3 + 1] * inv_ell;
    const float z2 = Z[lane * 3 + 2] * inv_ell;

#pragma clang loop unroll(disable)
    for (int j = 0; j < 64; ++j) {
        float dx = z0 - RDLANE(z0, j);
        float dy = z1 - RDLANE(z1, j);
        float dz = z2 - RDLANE(z2, j);
        float sq = dx * dx + dy * dy + dz * dz;
        Lsh[lane * 65 + j] = sf2 * EXP2F(-0.5f * LOG2E * sq);
    }
    __syncthreads();

    Rows r;
    load_row(r, &Lsh[lane * 65], std::make_integer_sequence<int, 64>{});

    chol_phase< 0, 32,  0>(r, Lsh, lane);
    chol_phase<32, 48, 32>(r, Lsh, lane);
    chol_phase<48, 64, 48>(r, Lsh, lane);
    __syncthreads();

    float s0 = U[lane * 2 + 0];
    float s1 = U[lane * 2 + 1];
    float w0v = 0.0f, w1v = 0.0f;
#pragma unroll 8
    for (int i = 63; i >= 0; --i) {
        float a   = Lsh[i * 65 + lane];    // L[i][lane]; lane i: 1/L[i][i]
        float rdi = RDLANE(a, i);          // 1/L[i][i]
        float w0  = RDLANE(s0, i) * rdi;   // W[i][0]
        float w1  = RDLANE(s1, i) * rdi;   // W[i][1]
        bool  me  = (lane == i);
        w0v = me ? w0 : w0v;
        w1v = me ? w1 : w1v;
        s0 = fmaf(-a, w0, s0);             // lanes >= i polluted after use
        s1 = fmaf(-a, w1, s1);
    }

    const float dm = -0.5f * LOG2E * (z0 * z0 + z1 * z1 + z2 * z2);
    float4* ws4 = (float4*)ws;
    ws4[lane * 2 + 0] = make_float4(z0, z1, z2, dm);
    ws4[lane * 2 + 1] = make_float4(sf2 * w0v, sf2 * w1v, 0.0f, 0.0f);
}

// ---------------------------------------------------------------------------
// Kernel 2, R12: per-m constants via literal-lane v_readlane.
// R11 evidence: per-m s_load (69.7us, VALUBusy 30%) and per-m ds_read (~35us
// timed) both stall the unrolled m-loop on lgkmcnt. Now lane m holds ws
// struct m in VGPRs (two coalesced float4 loads, ONE vmcnt wait at start);
// the m-loop reads constants with v_readlane (literal lane) -- pure VALU,
// no memory ops, no waits. Serial chain = the fma/exp pipeline itself.
// ---------------------------------------------------------------------------
__global__ __launch_bounds__(256) void gp_forward(const float* __restrict__ X,
                                                  const float* __restrict__ ws,
                                                  const float* __restrict__ ell_p,
                                                  float* __restrict__ out, int n) {
    const int lane = threadIdx.x & 63;
    // Lane m of every wave owns ws struct m: {z0,z1,z2,dm} and {w0,w1,-,-}.
    const float4 ca = ((const float4*)ws)[2 * lane + 0];
    const float4 cb = ((const float4*)ws)[2 * lane + 1];
    const float inv_ell = 1.0f / ell_p[0];

    const int base = blockIdx.x * (256 * 4) + threadIdx.x;

    float xt0[4], xt1[4], xt2[4], c[4];
#pragma unroll
    for (int p = 0; p < 4; ++p) {
        int i = base + p * 256;
        int ii = (i < n) ? i : 0;            // clamp; result masked on store
        float xs0 = X[ii * 3 + 0] * inv_ell;
        float xs1 = X[ii * 3 + 1] * inv_ell;
        float xs2 = X[ii * 3 + 2] * inv_ell;
        c[p]  = -0.5f * LOG2E * (xs0 * xs0 + xs1 * xs1 + xs2 * xs2);
        xt0[p] = xs0 * LOG2E;
        xt1[p] = xs1 * LOG2E;
        xt2[p] = xs2 * LOG2E;
    }

    float acc0[4] = {0.f, 0.f, 0.f, 0.f};
    float acc1[4] = {0.f, 0.f, 0.f, 0.f};

#pragma unroll
    for (int m = 0; m < 64; ++m) {
        // Literal-lane readlane: VALU-only broadcast into SGPRs, zero waits.
        const float z0 = RDLANE(ca.x, m);
        const float z1 = RDLANE(ca.y, m);
        const float z2 = RDLANE(ca.z, m);
        const float dm = RDLANE(ca.w, m);
        const float w0 = RDLANE(cb.x, m);
        const float w1 = RDLANE(cb.y, m);
#pragma unroll
        for (int p = 0; p < 4; ++p) {
            float arg = fmaf(xt0[p], z0,
                        fmaf(xt1[p], z1,
                        fmaf(xt2[p], z2, c[p] + dm)));
            float e = EXP2F(arg);
            acc0[p] = fmaf(e, w0, acc0[p]);
            acc1[p] = fmaf(e, w1, acc1[p]);
        }
    }

    float2* out2 = (float2*)out;
#pragma unroll
    for (int p = 0; p < 4; ++p) {
        int i = base + p * 256;
        if (i < n) out2[i] = make_float2(acc0[p], acc1[p]);
    }
}

extern "C" void kernel_launch(void* const* d_in, const int* in_sizes, int n_in,
                              void* d_out, int out_size, void* d_ws, size_t ws_size,
                              hipStream_t stream) {
    // setup_inputs order: t, X, Z, U, sf, ell
    const float* X    = (const float*)d_in[1];
    const float* Z    = (const float*)d_in[2];
    const float* U    = (const float*)d_in[3];
    const float* sf   = (const float*)d_in[4];
    const float* ell  = (const float*)d_in[5];
    float* out = (float*)d_out;
    float* ws  = (float*)d_ws;
    const int N = in_sizes[1] / 3;

    gp_precompute<<<1, 64, 0, stream>>>(Z, U, sf, ell, ws);

    const int PTS_PER_BLOCK = 256 * 4;
    const int blocks = (N + PTS_PER_BLOCK - 1) / PTS_PER_BLOCK;
    gp_forward<<<blocks, 256, 0, stream>>>(X, ws, ell, out, N);
}

// Round 13
// 56.316 us; speedup vs baseline: 1.1188x; 1.0337x over previous
//
#include <hip/hip_runtime.h>
#include <hip/hip_bf16.h>
#include <utility>

#define LOG2E 1.4426950408889634f

#if __has_builtin(__builtin_amdgcn_exp2f)
#define EXP2F(x) __builtin_amdgcn_exp2f(x)
#else
#define EXP2F(x) exp2f(x)
#endif

#if __has_builtin(__builtin_amdgcn_rsqf)
#define RSQ(x) __builtin_amdgcn_rsqf(x)
#else
#define RSQ(x) (1.0f / sqrtf(x))
#endif

// readlane: lane may be a literal OR a runtime-uniform (SGPR) value.
#define RDLANE(x, l) __int_as_float(__builtin_amdgcn_readlane(__float_as_int(x), (l)))

// ---------------------------------------------------------------------------
// Kernel 1 (byte-identical to R9): rolled-outer / padded-unrolled-inner
// Cholesky, one wave. R9 evidence: dropped out of rocprof top-5.
// ---------------------------------------------------------------------------
typedef float f16v __attribute__((ext_vector_type(16)));
struct Rows { f16v v0, v1, v2, v3; };

template<int J> __device__ __forceinline__ float getR(const Rows& r) {
    if constexpr (J < 16)      return r.v0[J];
    else if constexpr (J < 32) return r.v1[J - 16];
    else if constexpr (J < 48) return r.v2[J - 32];
    else                       return r.v3[J - 48];
}
template<int J> __device__ __forceinline__ void setR(Rows& r, float x) {
    if constexpr (J < 16)      r.v0[J] = x;
    else if constexpr (J < 32) r.v1[J - 16] = x;
    else if constexpr (J < 48) r.v2[J - 32] = x;
    else                       r.v3[J - 48] = x;
}

template<int LO, int W>
__device__ __forceinline__ float selR(const Rows& r, int k) {
    if constexpr (W == 1) {
        return getR<LO>(r);
    } else {
        float lo = selR<LO, W / 2>(r, k);
        float hi = selR<LO + W / 2, W / 2>(r, k);
        return (k & (W / 2)) ? hi : lo;   // uniform cond -> cndmask, CSE'd
    }
}

template<int J>
__device__ __forceinline__ void upd1(Rows& r, float lk) {
    float ljk = RDLANE(lk, J);                 // literal source lane
    setR<J>(r, fmaf(-lk, ljk, getR<J>(r)));
}
template<int LO, int... Js>
__device__ __forceinline__ void upd_seq(Rows& r, float lk,
                                        std::integer_sequence<int, Js...>) {
    (upd1<LO + Js>(r, lk), ...);
}

template<int... Js>
__device__ __forceinline__ void load_row(Rows& r, const float* Lrow,
                                         std::integer_sequence<int, Js...>) {
    (setR<Js>(r, Lrow[Js]), ...);
}

template<int KLO, int KHI, int ULO>
__device__ __forceinline__ void chol_phase(Rows& r, float* Lsh, int lane) {
#pragma clang loop unroll(disable)
    for (int k = KLO; k < KHI; ++k) {
        float rk  = selR<ULO, 64 - ULO>(r, k); // A[l][k] (valid l >= k)
        float dk  = RDLANE(rk, k);             // A[k][k], uniform
        float inv = RSQ(dk);                   // 1/L[k][k]
        float lk  = rk * inv;                  // L[l][k]
        float st  = (lane == k) ? inv : lk;    // diag slot stores reciprocal
        Lsh[lane * 65 + k] = st;               // sink column k (conflict-free)
        upd_seq<ULO>(r, lk, std::make_integer_sequence<int, 64 - ULO>{});
    }
}

__global__ __launch_bounds__(64, 1)
void gp_precompute(const float* __restrict__ Z, const float* __restrict__ U,
                   const float* __restrict__ sf_p, const float* __restrict__ ell_p,
                   float* __restrict__ ws) {
    __shared__ float Lsh[64 * 65];
    const int lane = threadIdx.x;          // 64 threads = 1 wave
    const float sf  = sf_p[0];
    const float ell = ell_p[0];
    const float inv_ell = 1.0f / ell;
    const float sf2 = sf * sf;

    const float z0 = Z[lane * 3 + 0] * inv_ell;
    const float z1 = Z[lane * 3 + 1] * inv_ell;
    const float z2 = Z[lane * 3 + 2] * inv_ell;

#pragma clang loop unroll(disable)
    for (int j = 0; j < 64; ++j) {
        float dx = z0 - RDLANE(z0, j);
        float dy = z1 - RDLANE(z1, j);
        float dz = z2 - RDLANE(z2, j);
        float sq = dx * dx + dy * dy + dz * dz;
        Lsh[lane * 65 + j] = sf2 * EXP2F(-0.5f * LOG2E * sq);
    }
    __syncthreads();

    Rows r;
    load_row(r, &Lsh[lane * 65], std::make_integer_sequence<int, 64>{});

    chol_phase< 0, 32,  0>(r, Lsh, lane);
    chol_phase<32, 48, 32>(r, Lsh, lane);
    chol_phase<48, 64, 48>(r, Lsh, lane);
    __syncthreads();

    float s0 = U[lane * 2 + 0];
    float s1 = U[lane * 2 + 1];
    float w0v = 0.0f, w1v = 0.0f;
#pragma unroll 8
    for (int i = 63; i >= 0; --i) {
        float a   = Lsh[i * 65 + lane];    // L[i][lane]; lane i: 1/L[i][i]
        float rdi = RDLANE(a, i);          // 1/L[i][i]
        float w0  = RDLANE(s0, i) * rdi;   // W[i][0]
        float w1  = RDLANE(s1, i) * rdi;   // W[i][1]
        bool  me  = (lane == i);
        w0v = me ? w0 : w0v;
        w1v = me ? w1 : w1v;
        s0 = fmaf(-a, w0, s0);             // lanes >= i polluted after use
        s1 = fmaf(-a, w1, s1);
    }

    const float dm = -0.5f * LOG2E * (z0 * z0 + z1 * z1 + z2 * z2);
    float4* ws4 = (float4*)ws;
    ws4[lane * 2 + 0] = make_float4(z0, z1, z2, dm);
    ws4[lane * 2 + 1] = make_float4(sf2 * w0v, sf2 * w1v, 0.0f, 0.0f);
}

// ---------------------------------------------------------------------------
// Kernel 2, R13: back to LDS broadcasts (R11 s_load and R12 readlane both
// regressed: 30% VALUBusy from per-m wait hazards). Fixes vs R1's LDS loop:
//  - 2 points/thread -> 1954 blocks = 7.6 blocks/CU (2x resident waves/SIMD;
//    R1/R12 had 3.8 blocks/CU, occupancy ~23%)
//  - FULL 64-iter m-unroll: scheduler hoists ds_reads many iters ahead,
//    hiding the ~120cyc LDS latency (R1's unroll-4 couldn't)
//  - consecutive point pair per thread: X via 3x float2 (coalesced), out via
//    one aligned float4 store
// ---------------------------------------------------------------------------
__global__ __launch_bounds__(256) void gp_forward(const float* __restrict__ X,
                                                  const float* __restrict__ ws,
                                                  const float* __restrict__ ell_p,
                                                  float* __restrict__ out, int n) {
    __shared__ float4 P[128];   // 64 structs of {zs0,zs1,zs2,dm | w0,w1,0,0}
    for (int i = threadIdx.x; i < 128; i += 256)
        P[i] = ((const float4*)ws)[i];
    const float inv_ell = 1.0f / ell_p[0];
    __syncthreads();

    const int t  = blockIdx.x * 256 + threadIdx.x;  // global thread id
    const int i0 = 2 * t;                            // first of 2 points

    // Load 6 contiguous floats (2 points x 3 dims) as 3 aligned float2.
    float p00, p01, p02, p10, p11, p12;
    if (i0 + 1 < n) {
        const float2* X2 = (const float2*)X;
        float2 xa = X2[3 * t + 0];
        float2 xb = X2[3 * t + 1];
        float2 xc = X2[3 * t + 2];
        p00 = xa.x; p01 = xa.y; p02 = xb.x;
        p10 = xb.y; p11 = xc.x; p12 = xc.y;
    } else if (i0 < n) {
        p00 = X[3 * i0 + 0]; p01 = X[3 * i0 + 1]; p02 = X[3 * i0 + 2];
        p10 = p00; p11 = p01; p12 = p02;
    } else {
        p00 = p01 = p02 = p10 = p11 = p12 = 0.0f;
    }

    float xt0[2], xt1[2], xt2[2], c[2];
    {
        float xs0 = p00 * inv_ell, xs1 = p01 * inv_ell, xs2 = p02 * inv_ell;
        c[0]  = -0.5f * LOG2E * (xs0 * xs0 + xs1 * xs1 + xs2 * xs2);
        xt0[0] = xs0 * LOG2E; xt1[0] = xs1 * LOG2E; xt2[0] = xs2 * LOG2E;
        xs0 = p10 * inv_ell; xs1 = p11 * inv_ell; xs2 = p12 * inv_ell;
        c[1]  = -0.5f * LOG2E * (xs0 * xs0 + xs1 * xs1 + xs2 * xs2);
        xt0[1] = xs0 * LOG2E; xt1[1] = xs1 * LOG2E; xt2[1] = xs2 * LOG2E;
    }

    float acc0[2] = {0.f, 0.f};
    float acc1[2] = {0.f, 0.f};

#pragma unroll
    for (int m = 0; m < 64; ++m) {          // FULL unroll: static indices,
        const float4 a = P[2 * m + 0];      // ds_reads hoisted far ahead
        const float4 b = P[2 * m + 1];
#pragma unroll
        for (int p = 0; p < 2; ++p) {
            float arg = fmaf(xt0[p], a.x,
                        fmaf(xt1[p], a.y,
                        fmaf(xt2[p], a.z, c[p] + a.w)));
            float e = EXP2F(arg);
            acc0[p] = fmaf(e, b.x, acc0[p]);
            acc1[p] = fmaf(e, b.y, acc1[p]);
        }
    }

    if (i0 + 1 < n) {
        ((float4*)out)[t] = make_float4(acc0[0], acc1[0], acc0[1], acc1[1]);
    } else if (i0 < n) {
        ((float2*)out)[i0] = make_float2(acc0[0], acc1[0]);
    }
}

extern "C" void kernel_launch(void* const* d_in, const int* in_sizes, int n_in,
                              void* d_out, int out_size, void* d_ws, size_t ws_size,
                              hipStream_t stream) {
    // setup_inputs order: t, X, Z, U, sf, ell
    const float* X    = (const float*)d_in[1];
    const float* Z    = (const float*)d_in[2];
    const float* U    = (const float*)d_in[3];
    const float* sf   = (const float*)d_in[4];
    const float* ell  = (const float*)d_in[5];
    float* out = (float*)d_out;
    float* ws  = (float*)d_ws;
    const int N = in_sizes[1] / 3;

    gp_precompute<<<1, 64, 0, stream>>>(Z, U, sf, ell, ws);

    const int PTS_PER_BLOCK = 256 * 2;      // 2 points per thread
    const int blocks = (N + PTS_PER_BLOCK - 1) / PTS_PER_BLOCK;
    gp_forward<<<blocks, 256, 0, stream>>>(X, ws, ell, out, N);
}

// Round 14
// 41.421 us; speedup vs baseline: 1.5211x; 1.3596x over previous
//
#include <hip/hip_runtime.h>
#include <hip/hip_bf16.h>
#include <utility>

#define LOG2E 1.4426950408889634f

#if __has_builtin(__builtin_amdgcn_exp2f)
#define EXP2F(x) __builtin_amdgcn_exp2f(x)
#else
#define EXP2F(x) exp2f(x)
#endif

#if __has_builtin(__builtin_amdgcn_rsqf)
#define RSQ(x) __builtin_amdgcn_rsqf(x)
#else
#define RSQ(x) (1.0f / sqrtf(x))
#endif

// readlane: lane may be a literal OR a runtime-uniform (SGPR) value.
#define RDLANE(x, l) __int_as_float(__builtin_amdgcn_readlane(__float_as_int(x), (l)))

// ---------------------------------------------------------------------------
// Kernel 1 (byte-identical to R9): rolled-outer / padded-unrolled-inner
// Cholesky, one wave. R9 evidence: dropped out of rocprof top-5.
// ---------------------------------------------------------------------------
typedef float f16v __attribute__((ext_vector_type(16)));
struct Rows { f16v v0, v1, v2, v3; };

template<int J> __device__ __forceinline__ float getR(const Rows& r) {
    if constexpr (J < 16)      return r.v0[J];
    else if constexpr (J < 32) return r.v1[J - 16];
    else if constexpr (J < 48) return r.v2[J - 32];
    else                       return r.v3[J - 48];
}
template<int J> __device__ __forceinline__ void setR(Rows& r, float x) {
    if constexpr (J < 16)      r.v0[J] = x;
    else if constexpr (J < 32) r.v1[J - 16] = x;
    else if constexpr (J < 48) r.v2[J - 32] = x;
    else                       r.v3[J - 48] = x;
}

template<int LO, int W>
__device__ __forceinline__ float selR(const Rows& r, int k) {
    if constexpr (W == 1) {
        return getR<LO>(r);
    } else {
        float lo = selR<LO, W / 2>(r, k);
        float hi = selR<LO + W / 2, W / 2>(r, k);
        return (k & (W / 2)) ? hi : lo;   // uniform cond -> cndmask, CSE'd
    }
}

template<int J>
__device__ __forceinline__ void upd1(Rows& r, float lk) {
    float ljk = RDLANE(lk, J);                 // literal source lane
    setR<J>(r, fmaf(-lk, ljk, getR<J>(r)));
}
template<int LO, int... Js>
__device__ __forceinline__ void upd_seq(Rows& r, float lk,
                                        std::integer_sequence<int, Js...>) {
    (upd1<LO + Js>(r, lk), ...);
}

template<int... Js>
__device__ __forceinline__ void load_row(Rows& r, const float* Lrow,
                                         std::integer_sequence<int, Js...>) {
    (setR<Js>(r, Lrow[Js]), ...);
}

template<int KLO, int KHI, int ULO>
__device__ __forceinline__ void chol_phase(Rows& r, float* Lsh, int lane) {
#pragma clang loop unroll(disable)
    for (int k = KLO; k < KHI; ++k) {
        float rk  = selR<ULO, 64 - ULO>(r, k); // A[l][k] (valid l >= k)
        float dk  = RDLANE(rk, k);             // A[k][k], uniform
        float inv = RSQ(dk);                   // 1/L[k][k]
        float lk  = rk * inv;                  // L[l][k]
        float st  = (lane == k) ? inv : lk;    // diag slot stores reciprocal
        Lsh[lane * 65 + k] = st;               // sink column k (conflict-free)
        upd_seq<ULO>(r, lk, std::make_integer_sequence<int, 64 - ULO>{});
    }
}

__global__ __launch_bounds__(64, 1)
void gp_precompute(const float* __restrict__ Z, const float* __restrict__ U,
                   const float* __restrict__ sf_p, const float* __restrict__ ell_p,
                   float* __restrict__ ws) {
    __shared__ float Lsh[64 * 65];
    const int lane = threadIdx.x;          // 64 threads = 1 wave
    const float sf  = sf_p[0];
    const float ell = ell_p[0];
    const float inv_ell = 1.0f / ell;
    const float sf2 = sf * sf;

    const float z0 = Z[lane * 3 + 0] * inv_ell;
    const float z1 = Z[lane * 3 + 1] * inv_ell;
    const float z2 = Z[lane * 3 + 2] * inv_ell;

#pragma clang loop unroll(disable)
    for (int j = 0; j < 64; ++j) {
        float dx = z0 - RDLANE(z0, j);
        float dy = z1 - RDLANE(z1, j);
        float dz = z2 - RDLANE(z2, j);
        float sq = dx * dx + dy * dy + dz * dz;
        Lsh[lane * 65 + j] = sf2 * EXP2F(-0.5f * LOG2E * sq);
    }
    __syncthreads();

    Rows r;
    load_row(r, &Lsh[lane * 65], std::make_integer_sequence<int, 64>{});

    chol_phase< 0, 32,  0>(r, Lsh, lane);
    chol_phase<32, 48, 32>(r, Lsh, lane);
    chol_phase<48, 64, 48>(r, Lsh, lane);
    __syncthreads();

    float s0 = U[lane * 2 + 0];
    float s1 = U[lane * 2 + 1];
    float w0v = 0.0f, w1v = 0.0f;
#pragma unroll 8
    for (int i = 63; i >= 0; --i) {
        float a   = Lsh[i * 65 + lane];    // L[i][lane]; lane i: 1/L[i][i]
        float rdi = RDLANE(a, i);          // 1/L[i][i]
        float w0  = RDLANE(s0, i) * rdi;   // W[i][0]
        float w1  = RDLANE(s1, i) * rdi;   // W[i][1]
        bool  me  = (lane == i);
        w0v = me ? w0 : w0v;
        w1v = me ? w1 : w1v;
        s0 = fmaf(-a, w0, s0);             // lanes >= i polluted after use
        s1 = fmaf(-a, w1, s1);
    }

    const float dm = -0.5f * LOG2E * (z0 * z0 + z1 * z1 + z2 * z2);
    float4* ws4 = (float4*)ws;
    ws4[lane * 2 + 0] = make_float4(z0, z1, z2, dm);
    ws4[lane * 2 + 1] = make_float4(sf2 * w0v, sf2 * w1v, 0.0f, 0.0f);
}

// ---------------------------------------------------------------------------
// Kernel 2, R14: R1's proven LDS-broadcast m-loop (unroll 4, ~80 VGPR) +
// R13's 2-pts/thread grid (1954 blocks = 7.6 blocks/CU, ~2x resident waves
// vs R1's 977) + coalesced float2 X loads / single float4 store.
// R13's only real defect was the full m-unroll -> VGPR 200 -> occupancy 9%;
// this keeps the register-lean loop body with the bigger grid.
// ---------------------------------------------------------------------------
__global__ __launch_bounds__(256) void gp_forward(const float* __restrict__ X,
                                                  const float* __restrict__ ws,
                                                  const float* __restrict__ ell_p,
                                                  float* __restrict__ out, int n) {
    __shared__ float4 P[128];   // 64 structs of {zs0,zs1,zs2,dm | w0,w1,0,0}
    for (int i = threadIdx.x; i < 128; i += 256)
        P[i] = ((const float4*)ws)[i];
    const float inv_ell = 1.0f / ell_p[0];
    __syncthreads();

    const int t  = blockIdx.x * 256 + threadIdx.x;  // global thread id
    const int i0 = 2 * t;                            // first of 2 points

    // Load 6 contiguous floats (2 points x 3 dims) as 3 aligned float2.
    float p00, p01, p02, p10, p11, p12;
    if (i0 + 1 < n) {
        const float2* X2 = (const float2*)X;
        float2 xa = X2[3 * t + 0];
        float2 xb = X2[3 * t + 1];
        float2 xc = X2[3 * t + 2];
        p00 = xa.x; p01 = xa.y; p02 = xb.x;
        p10 = xb.y; p11 = xc.x; p12 = xc.y;
    } else if (i0 < n) {
        p00 = X[3 * i0 + 0]; p01 = X[3 * i0 + 1]; p02 = X[3 * i0 + 2];
        p10 = p00; p11 = p01; p12 = p02;
    } else {
        p00 = p01 = p02 = p10 = p11 = p12 = 0.0f;
    }

    float xt0[2], xt1[2], xt2[2], c[2];
    {
        float xs0 = p00 * inv_ell, xs1 = p01 * inv_ell, xs2 = p02 * inv_ell;
        c[0]  = -0.5f * LOG2E * (xs0 * xs0 + xs1 * xs1 + xs2 * xs2);
        xt0[0] = xs0 * LOG2E; xt1[0] = xs1 * LOG2E; xt2[0] = xs2 * LOG2E;
        xs0 = p10 * inv_ell; xs1 = p11 * inv_ell; xs2 = p12 * inv_ell;
        c[1]  = -0.5f * LOG2E * (xs0 * xs0 + xs1 * xs1 + xs2 * xs2);
        xt0[1] = xs0 * LOG2E; xt1[1] = xs1 * LOG2E; xt2[1] = xs2 * LOG2E;
    }

    float acc0[2] = {0.f, 0.f};
    float acc1[2] = {0.f, 0.f};

#pragma unroll 4
    for (int m = 0; m < 64; ++m) {          // register-lean: 4-iter window
        const float4 a = P[2 * m + 0];
        const float4 b = P[2 * m + 1];
#pragma unroll
        for (int p = 0; p < 2; ++p) {
            float arg = fmaf(xt0[p], a.x,
                        fmaf(xt1[p], a.y,
                        fmaf(xt2[p], a.z, c[p] + a.w)));
            float e = EXP2F(arg);
            acc0[p] = fmaf(e, b.x, acc0[p]);
            acc1[p] = fmaf(e, b.y, acc1[p]);
        }
    }

    if (i0 + 1 < n) {
        ((float4*)out)[t] = make_float4(acc0[0], acc1[0], acc0[1], acc1[1]);
    } else if (i0 < n) {
        ((float2*)out)[i0] = make_float2(acc0[0], acc1[0]);
    }
}

extern "C" void kernel_launch(void* const* d_in, const int* in_sizes, int n_in,
                              void* d_out, int out_size, void* d_ws, size_t ws_size,
                              hipStream_t stream) {
    // setup_inputs order: t, X, Z, U, sf, ell
    const float* X    = (const float*)d_in[1];
    const float* Z    = (const float*)d_in[2];
    const float* U    = (const float*)d_in[3];
    const float* sf   = (const float*)d_in[4];
    const float* ell  = (const float*)d_in[5];
    float* out = (float*)d_out;
    float* ws  = (float*)d_ws;
    const int N = in_sizes[1] / 3;

    gp_precompute<<<1, 64, 0, stream>>>(Z, U, sf, ell, ws);

    const int PTS_PER_BLOCK = 256 * 2;      // 2 points per thread
    const int blocks = (N + PTS_PER_BLOCK - 1) / PTS_PER_BLOCK;
    gp_forward<<<blocks, 256, 0, stream>>>(X, ws, ell, out, N);
}